// Round 3
// baseline (1827.418 us; speedup 1.0000x reference)
//
#include <hip/hip_runtime.h>

#define NN 100000
#define EE 1600000
#define DD 64
#define CC 10
#define GG 512
#define LL 5
#define NPAD 100352            // NN padded to 256*392
#define N64 (NN * DD)

typedef short bf16x8 __attribute__((ext_vector_type(8)));
typedef float f32x4  __attribute__((ext_vector_type(4)));
union U16 { uint4 u; bf16x8 h; };

__device__ __forceinline__ float bits2f(unsigned int b) { return __uint_as_float(b); }
__device__ __forceinline__ unsigned short f2bf_rne(float v) {
    unsigned int b = __float_as_uint(v);
    return (unsigned short)((b + 0x7fffu + ((b >> 16) & 1u)) >> 16);
}
__device__ __forceinline__ void unpack8(uint4 u, float* f) {
    f[0] = bits2f(u.x << 16); f[1] = bits2f(u.x & 0xffff0000u);
    f[2] = bits2f(u.y << 16); f[3] = bits2f(u.y & 0xffff0000u);
    f[4] = bits2f(u.z << 16); f[5] = bits2f(u.z & 0xffff0000u);
    f[6] = bits2f(u.w << 16); f[7] = bits2f(u.w & 0xffff0000u);
}
__device__ __forceinline__ uint4 pack8(const float* f) {
    uint4 u;
    u.x = (unsigned int)f2bf_rne(f[0]) | ((unsigned int)f2bf_rne(f[1]) << 16);
    u.y = (unsigned int)f2bf_rne(f[2]) | ((unsigned int)f2bf_rne(f[3]) << 16);
    u.z = (unsigned int)f2bf_rne(f[4]) | ((unsigned int)f2bf_rne(f[5]) << 16);
    u.w = (unsigned int)f2bf_rne(f[6]) | ((unsigned int)f2bf_rne(f[7]) << 16);
    return u;
}

// ================= prep: x fp32 -> bf16 =================
__global__ __launch_bounds__(256) void prep_x_k(const float* __restrict__ x,
                                                unsigned short* __restrict__ hb) {
    int tid = blockIdx.x * 256 + threadIdx.x;       // over NN*8
    if (tid >= NN * 8) return;
    const float* s = x + (size_t)tid * 8;
    float f[8];
    #pragma unroll
    for (int j = 0; j < 8; ++j) f[j] = s[j];
    ((uint4*)hb)[tid] = pack8(f);
}

// ================= prep: W -> transposed bf16 (Wt[c][k] = W[k][c]) =========
__global__ __launch_bounds__(256) void prep_w_k(const float* __restrict__ W1,
                                                const float* __restrict__ W2,
                                                unsigned short* __restrict__ wt) {
    int mat = blockIdx.x;                            // 0..7: 0-3 = W1 layers, 4-7 = W2
    const float* src = (mat < 4) ? (W1 + (size_t)mat * 4096)
                                 : (W2 + (size_t)(mat - 4) * 4096);
    for (int idx = threadIdx.x; idx < 4096; idx += 256) {
        int c = idx >> 6, k = idx & 63;
        wt[(size_t)mat * 4096 + c * 64 + k] = f2bf_rne(src[k * 64 + c]);
    }
}

// ================= CSR build =================
__global__ __launch_bounds__(256) void hist_k(const int* __restrict__ ei,
                                              int* __restrict__ deg) {
    int e = blockIdx.x * 256 + threadIdx.x;
    if (e < EE) atomicAdd(&deg[ei[EE + e]], 1);
}

__global__ __launch_bounds__(256) void scan1_k(const int* __restrict__ deg,
                                               int* __restrict__ offs,
                                               int* __restrict__ bsums) {
    __shared__ int s[256];
    int t = threadIdx.x;
    int i = blockIdx.x * 256 + t;
    int v = deg[i];
    s[t] = v;
    __syncthreads();
    #pragma unroll
    for (int d = 1; d < 256; d <<= 1) {
        int a = (t >= d) ? s[t - d] : 0;
        __syncthreads();
        s[t] += a;
        __syncthreads();
    }
    offs[i] = s[t] - v;
    if (t == 255) bsums[blockIdx.x] = s[255];
}

__global__ __launch_bounds__(512) void scan2_k(int* __restrict__ bsums) {
    __shared__ int s[512];
    int t = threadIdx.x;
    int v = (t < NPAD / 256) ? bsums[t] : 0;
    s[t] = v;
    __syncthreads();
    #pragma unroll
    for (int d = 1; d < 512; d <<= 1) {
        int a = (t >= d) ? s[t - d] : 0;
        __syncthreads();
        s[t] += a;
        __syncthreads();
    }
    if (t < NPAD / 256) bsums[t] = s[t] - v;
}

__global__ __launch_bounds__(256) void scan3_k(int* __restrict__ offs,
                                               const int* __restrict__ bsums,
                                               int* __restrict__ pos) {
    int i = blockIdx.x * 256 + threadIdx.x;
    int o = offs[i] + bsums[blockIdx.x];
    offs[i] = o;
    pos[i] = o;
}

__global__ __launch_bounds__(256) void fill_k(const int* __restrict__ ei,
                                              int* __restrict__ pos,
                                              int* __restrict__ adj) {
    int e = blockIdx.x * 256 + threadIdx.x;
    if (e >= EE) return;
    int dst = ei[EE + e];
    int p = atomicAdd(&pos[dst], 1);
    adj[p] = ei[e];
}

// ================= gather + GIN combine (bf16) =================
// 8 lanes per node; lane handles 8 bf16 features (16B).
__global__ __launch_bounds__(256) void gather_bf16_k(
    const unsigned short* __restrict__ h, const int* __restrict__ adj,
    const int* __restrict__ offs, const float* __restrict__ epsArr, int l,
    unsigned short* __restrict__ out)
{
    int t = threadIdx.x;
    int c8 = t & 7;
    int n = blockIdx.x * 32 + (t >> 3);
    if (n >= NN) return;
    float epsv = 1.0f + epsArr[l];

    uint4 a = ((const uint4*)(h + (size_t)n * DD))[c8];
    float acc[8], tmp[8];
    unpack8(a, acc);
    #pragma unroll
    for (int j = 0; j < 8; ++j) acc[j] *= epsv;

    int j = offs[n], end = offs[n + 1];
    for (; j + 1 < end; j += 2) {
        int s0 = adj[j], s1 = adj[j + 1];
        uint4 v0 = ((const uint4*)(h + (size_t)s0 * DD))[c8];
        uint4 v1 = ((const uint4*)(h + (size_t)s1 * DD))[c8];
        unpack8(v0, tmp);
        #pragma unroll
        for (int k = 0; k < 8; ++k) acc[k] += tmp[k];
        unpack8(v1, tmp);
        #pragma unroll
        for (int k = 0; k < 8; ++k) acc[k] += tmp[k];
    }
    if (j < end) {
        uint4 v0 = ((const uint4*)(h + (size_t)adj[j] * DD))[c8];
        unpack8(v0, tmp);
        #pragma unroll
        for (int k = 0; k < 8; ++k) acc[k] += tmp[k];
    }
    ((uint4*)(out + (size_t)n * DD))[c8] = pack8(acc);
}

// ================= MFMA GEMM + fused BN-stats =================
// MODE 0: A = in (bf16, raw)
// MODE 1: A = relu(sc*in + sh) per feature k (BN1+ReLU on the fly)
// out z (bf16) = A @ W + bias ; stats shadow[copy][0:64]=sum, [64:128]=sumsq
template<int MODE>
__global__ __launch_bounds__(256) void gemm_mfma_k(
    const unsigned short* __restrict__ inA,
    const float* __restrict__ ssp,          // scale[64]|shift[64] (MODE 1)
    const unsigned short* __restrict__ wtm, // transposed bf16 W: [c][k]
    const float* __restrict__ bias,
    unsigned short* __restrict__ z,
    float* __restrict__ stats)
{
    const int t = threadIdx.x;
    const int lane = t & 63;
    const int w = t >> 6;                  // wave 0..3
    const int n15 = lane & 15;
    const int quad = lane >> 4;
    const int rowg0 = blockIdx.x * 64 + w * 16;   // first row of this wave

    // B fragments: 4 col-tiles x 2 k-steps, straight from global (L2-hot)
    U16 bfr[4][2];
    #pragma unroll
    for (int ct = 0; ct < 4; ++ct)
        #pragma unroll
        for (int ks = 0; ks < 2; ++ks)
            bfr[ct][ks].u = *(const uint4*)(wtm + (size_t)(ct * 16 + n15) * 64 + ks * 32 + quad * 8);

    // A fragments: 2 k-steps
    U16 afr[2];
    int arow = rowg0 + n15;
    int arowc = (arow < NN) ? arow : (NN - 1);     // clamp to stay in-buffer
    #pragma unroll
    for (int ks = 0; ks < 2; ++ks) {
        uint4 raw = *(const uint4*)(inA + (size_t)arowc * DD + ks * 32 + quad * 8);
        if (MODE == 0) {
            afr[ks].u = raw;
        } else {
            float f[8];
            unpack8(raw, f);
            int k0 = ks * 32 + quad * 8;
            float4 sc0 = *(const float4*)(ssp + k0);
            float4 sc1 = *(const float4*)(ssp + k0 + 4);
            float4 sh0 = *(const float4*)(ssp + 64 + k0);
            float4 sh1 = *(const float4*)(ssp + 64 + k0 + 4);
            f[0] = fmaxf(fmaf(sc0.x, f[0], sh0.x), 0.f);
            f[1] = fmaxf(fmaf(sc0.y, f[1], sh0.y), 0.f);
            f[2] = fmaxf(fmaf(sc0.z, f[2], sh0.z), 0.f);
            f[3] = fmaxf(fmaf(sc0.w, f[3], sh0.w), 0.f);
            f[4] = fmaxf(fmaf(sc1.x, f[4], sh1.x), 0.f);
            f[5] = fmaxf(fmaf(sc1.y, f[5], sh1.y), 0.f);
            f[6] = fmaxf(fmaf(sc1.z, f[6], sh1.z), 0.f);
            f[7] = fmaxf(fmaf(sc1.w, f[7], sh1.w), 0.f);
            afr[ks].u = pack8(f);
        }
    }

    const int copy = blockIdx.x & 31;
    #pragma unroll
    for (int ct = 0; ct < 4; ++ct) {
        f32x4 acc = {0.f, 0.f, 0.f, 0.f};
        acc = __builtin_amdgcn_mfma_f32_16x16x32_bf16(afr[0].h, bfr[ct][0].h, acc, 0, 0, 0);
        acc = __builtin_amdgcn_mfma_f32_16x16x32_bf16(afr[1].h, bfr[ct][1].h, acc, 0, 0, 0);

        int col = ct * 16 + n15;
        float bcol = bias[col];
        float s = 0.f, ss = 0.f;
        #pragma unroll
        for (int r = 0; r < 4; ++r) {
            int rg = rowg0 + quad * 4 + r;
            float v = acc[r] + bcol;
            if (rg < NN) {
                z[(size_t)rg * DD + col] = f2bf_rne(v);
                s += v;
                ss = fmaf(v, v, ss);
            }
        }
        s  += __shfl_xor(s, 16, 64);  s  += __shfl_xor(s, 32, 64);
        ss += __shfl_xor(ss, 16, 64); ss += __shfl_xor(ss, 32, 64);
        if (lane < 16) {
            atomicAdd(&stats[copy * 128 + ct * 16 + lane], s);
            atomicAdd(&stats[copy * 128 + 64 + ct * 16 + lane], ss);
        }
    }
}

// ================= BN finalize (sums 32 shadow copies) =================
__global__ void bn_final_k(const float* __restrict__ sh32,
                           const float* __restrict__ gamma, const float* __restrict__ beta,
                           int off, float* __restrict__ scaleshift)
{
    int f = threadIdx.x;   // 64 threads
    float S = 0.f, SS = 0.f;
    #pragma unroll
    for (int c = 0; c < 32; ++c) {
        S  += sh32[c * 128 + f];
        SS += sh32[c * 128 + 64 + f];
    }
    float inv_n = 1.0f / (float)NN;
    float mean = S * inv_n;
    float var  = SS * inv_n - mean * mean;
    float sc = gamma[off + f] * rsqrtf(var + 1e-5f);
    scaleshift[f] = sc;
    scaleshift[DD + f] = beta[off + f] - sc * mean;
}

// ================= outer BN apply + ReLU + pool + h(bf16) write ============
__global__ __launch_bounds__(256) void apply_bn_pool_k(
    const unsigned short* __restrict__ z2b, const float* __restrict__ ssp,
    const int* __restrict__ batch, unsigned short* __restrict__ hout,
    float* __restrict__ pooled)
{
    int tid = blockIdx.x * 256 + threadIdx.x;   // over NN*8
    if (tid >= NN * 8) return;
    int c8 = tid & 7;
    int node = tid >> 3;
    uint4 zr = ((const uint4*)z2b)[tid];
    float f[8];
    unpack8(zr, f);
    int k0 = c8 * 8;
    float4 sc0 = *(const float4*)(ssp + k0);
    float4 sc1 = *(const float4*)(ssp + k0 + 4);
    float4 sh0 = *(const float4*)(ssp + 64 + k0);
    float4 sh1 = *(const float4*)(ssp + 64 + k0 + 4);
    f[0] = fmaxf(fmaf(sc0.x, f[0], sh0.x), 0.f);
    f[1] = fmaxf(fmaf(sc0.y, f[1], sh0.y), 0.f);
    f[2] = fmaxf(fmaf(sc0.z, f[2], sh0.z), 0.f);
    f[3] = fmaxf(fmaf(sc0.w, f[3], sh0.w), 0.f);
    f[4] = fmaxf(fmaf(sc1.x, f[4], sh1.x), 0.f);
    f[5] = fmaxf(fmaf(sc1.y, f[5], sh1.y), 0.f);
    f[6] = fmaxf(fmaf(sc1.z, f[6], sh1.z), 0.f);
    f[7] = fmaxf(fmaf(sc1.w, f[7], sh1.w), 0.f);
    ((uint4*)hout)[tid] = pack8(f);
    float* pd = pooled + (size_t)batch[node] * DD + k0;
    #pragma unroll
    for (int j = 0; j < 8; ++j) atomicAdd(&pd[j], f[j]);
}

// ================= layer-0 pooling of raw x (fp32) =================
__global__ __launch_bounds__(256) void pool0_k(
    const float* __restrict__ x, const int* __restrict__ batch,
    float* __restrict__ pooled)
{
    int tid = blockIdx.x * 256 + threadIdx.x;
    if (tid >= NN * DD) return;
    int f = tid & 63;
    int i = tid >> 6;
    atomicAdd(&pooled[(size_t)batch[i] * DD + f], x[tid]);
}

// ================= jumping-knowledge readout =================
__global__ void readout_k(const float* __restrict__ pooled,
                          const float* __restrict__ Wp, const float* __restrict__ bp,
                          float* __restrict__ out)
{
    int gc = blockIdx.x * blockDim.x + threadIdx.x;
    if (gc >= GG * CC) return;
    int g = gc / CC, c = gc - g * CC;
    float acc = 0.f;
    for (int l = 0; l < LL; ++l) {
        acc += bp[l * CC + c];
        const float* p  = pooled + ((size_t)l * GG + g) * DD;
        const float* wv = Wp + (size_t)l * DD * CC + c;
        #pragma unroll 8
        for (int f = 0; f < DD; ++f) acc = fmaf(p[f], wv[f * CC], acc);
    }
    out[gc] = acc;
}

extern "C" void kernel_launch(void* const* d_in, const int* in_sizes, int n_in,
                              void* d_out, int out_size, void* d_ws, size_t ws_size,
                              hipStream_t stream) {
    const float* x     = (const float*)d_in[0];
    const int*   ei    = (const int*)d_in[1];
    const int*   batch = (const int*)d_in[2];
    const float* eps   = (const float*)d_in[3];
    const float* W1    = (const float*)d_in[4];
    const float* b1    = (const float*)d_in[5];
    const float* g1    = (const float*)d_in[6];
    const float* be1   = (const float*)d_in[7];
    const float* W2    = (const float*)d_in[8];
    const float* b2    = (const float*)d_in[9];
    const float* gout  = (const float*)d_in[10];
    const float* beout = (const float*)d_in[11];
    const float* Wp    = (const float*)d_in[12];
    const float* bp    = (const float*)d_in[13];
    float* out = (float*)d_out;

    float* pooled = (float*)d_ws;                       // LL*GG*DD
    float* stats1 = pooled + (size_t)LL * GG * DD;      // 32*128
    float* stats2 = stats1 + 32 * 128;                  // 32*128
    float* bnp    = stats2 + 32 * 128;                  // 256 (sc1,sh1 | sc2,sh2)
    unsigned short* hb    = (unsigned short*)(bnp + 256);
    unsigned short* combA = hb + N64;
    unsigned short* z1b   = combA + N64;
    unsigned short* z2b   = z1b + N64;
    unsigned short* wt    = z2b + N64;                  // 8*4096 bf16
    int* deg   = (int*)(wt + 8 * 4096);
    int* offs  = deg + NPAD + 256;
    int* pos   = offs + NPAD + 256;
    int* bsums = pos + NPAD;
    int* adj   = bsums + 512;

    // ---- prep (once per call) ----
    prep_x_k<<<(NN * 8 + 255) / 256, 256, 0, stream>>>(x, hb);
    prep_w_k<<<8, 256, 0, stream>>>(W1, W2, wt);

    // ---- CSR build ----
    hipMemsetAsync(deg, 0, NPAD * sizeof(int), stream);
    hist_k<<<(EE + 255) / 256, 256, 0, stream>>>(ei, deg);
    scan1_k<<<NPAD / 256, 256, 0, stream>>>(deg, offs, bsums);
    scan2_k<<<1, 512, 0, stream>>>(bsums);
    scan3_k<<<NPAD / 256, 256, 0, stream>>>(offs, bsums, pos);
    fill_k<<<(EE + 255) / 256, 256, 0, stream>>>(ei, pos, adj);

    hipMemsetAsync(pooled, 0, (size_t)LL * GG * DD * sizeof(float), stream);
    pool0_k<<<(NN * DD + 255) / 256, 256, 0, stream>>>(x, batch, pooled);

    const int gemm_grid = (NN + 63) / 64;
    for (int l = 0; l < LL - 1; ++l) {
        hipMemsetAsync(stats1, 0, 2 * 32 * 128 * sizeof(float), stream);
        gather_bf16_k<<<(NN + 31) / 32, 256, 0, stream>>>(hb, adj, offs, eps, l, combA);
        gemm_mfma_k<0><<<gemm_grid, 256, 0, stream>>>(
            combA, bnp, wt + (size_t)l * 4096, b1 + l * DD, z1b, stats1);
        bn_final_k<<<1, 64, 0, stream>>>(stats1, g1, be1, l * DD, bnp);
        gemm_mfma_k<1><<<gemm_grid, 256, 0, stream>>>(
            z1b, bnp, wt + (size_t)(4 + l) * 4096, b2 + l * DD, z2b, stats2);
        bn_final_k<<<1, 64, 0, stream>>>(stats2, gout, beout, l * DD, bnp + 128);
        apply_bn_pool_k<<<(NN * 8 + 255) / 256, 256, 0, stream>>>(
            z2b, bnp + 128, batch, hb, pooled + (size_t)(l + 1) * GG * DD);
    }
    readout_k<<<(GG * CC + 255) / 256, 256, 0, stream>>>(pooled, Wp, bp, out);
}

// Round 4
// 825.164 us; speedup vs baseline: 2.2146x; 2.2146x over previous
//
#include <hip/hip_runtime.h>

#define NN 100000
#define EE 1600000
#define DD 64
#define CC 10
#define GG 512
#define LL 5
#define NPAD 100352            // NN padded to 256*392
#define N64 (NN * DD)

typedef short bf16x8 __attribute__((ext_vector_type(8)));
typedef float f32x4  __attribute__((ext_vector_type(4)));
union U16 { uint4 u; bf16x8 h; };

__device__ __forceinline__ float bits2f(unsigned int b) { return __uint_as_float(b); }
__device__ __forceinline__ float bf2f(unsigned short s) { return __uint_as_float((unsigned int)s << 16); }
__device__ __forceinline__ unsigned short f2bf_rne(float v) {
    unsigned int b = __float_as_uint(v);
    return (unsigned short)((b + 0x7fffu + ((b >> 16) & 1u)) >> 16);
}
__device__ __forceinline__ void unpack8(uint4 u, float* f) {
    f[0] = bits2f(u.x << 16); f[1] = bits2f(u.x & 0xffff0000u);
    f[2] = bits2f(u.y << 16); f[3] = bits2f(u.y & 0xffff0000u);
    f[4] = bits2f(u.z << 16); f[5] = bits2f(u.z & 0xffff0000u);
    f[6] = bits2f(u.w << 16); f[7] = bits2f(u.w & 0xffff0000u);
}
__device__ __forceinline__ uint4 pack8(const float* f) {
    uint4 u;
    u.x = (unsigned int)f2bf_rne(f[0]) | ((unsigned int)f2bf_rne(f[1]) << 16);
    u.y = (unsigned int)f2bf_rne(f[2]) | ((unsigned int)f2bf_rne(f[3]) << 16);
    u.z = (unsigned int)f2bf_rne(f[4]) | ((unsigned int)f2bf_rne(f[5]) << 16);
    u.w = (unsigned int)f2bf_rne(f[6]) | ((unsigned int)f2bf_rne(f[7]) << 16);
    return u;
}

// ======== prep: x fp32 -> bf16 h, fused layer-0 segmented pooling ========
// lane = feature; quad q owns 64 contiguous nodes; flush on batch-id change.
__global__ __launch_bounds__(256) void prep_x_pool_k(
    const float* __restrict__ x, const int* __restrict__ batch,
    unsigned short* __restrict__ hb, float* __restrict__ pooled)
{
    int t = threadIdx.x;
    int f = t & 63;
    int q = t >> 6;
    int n0 = blockIdx.x * 256 + q * 64;
    float acc = 0.f;
    int curg = -1;
    for (int i = 0; i < 64; ++i) {
        int n = n0 + i;
        if (n >= NN) break;
        int g = batch[n];                        // wave-uniform load
        if (g != curg) {
            if (curg >= 0) atomicAdd(&pooled[(size_t)curg * DD + f], acc);
            acc = 0.f; curg = g;
        }
        float v = x[(size_t)n * DD + f];
        hb[(size_t)n * DD + f] = f2bf_rne(v);
        acc += v;
    }
    if (curg >= 0) atomicAdd(&pooled[(size_t)curg * DD + f], acc);
}

// ================= prep: W -> transposed bf16 (Wt[c][k] = W[k][c]) =========
__global__ __launch_bounds__(256) void prep_w_k(const float* __restrict__ W1,
                                                const float* __restrict__ W2,
                                                unsigned short* __restrict__ wt) {
    int mat = blockIdx.x;                            // 0..7: 0-3 = W1 layers, 4-7 = W2
    const float* src = (mat < 4) ? (W1 + (size_t)mat * 4096)
                                 : (W2 + (size_t)(mat - 4) * 4096);
    for (int idx = threadIdx.x; idx < 4096; idx += 256) {
        int c = idx >> 6, k = idx & 63;
        wt[(size_t)mat * 4096 + c * 64 + k] = f2bf_rne(src[k * 64 + c]);
    }
}

// ================= CSR build =================
__global__ __launch_bounds__(256) void hist_k(const int* __restrict__ ei,
                                              int* __restrict__ deg) {
    int e = blockIdx.x * 256 + threadIdx.x;
    if (e < EE) atomicAdd(&deg[ei[EE + e]], 1);
}

__global__ __launch_bounds__(256) void scan1_k(const int* __restrict__ deg,
                                               int* __restrict__ offs,
                                               int* __restrict__ bsums) {
    __shared__ int s[256];
    int t = threadIdx.x;
    int i = blockIdx.x * 256 + t;
    int v = deg[i];
    s[t] = v;
    __syncthreads();
    #pragma unroll
    for (int d = 1; d < 256; d <<= 1) {
        int a = (t >= d) ? s[t - d] : 0;
        __syncthreads();
        s[t] += a;
        __syncthreads();
    }
    offs[i] = s[t] - v;
    if (t == 255) bsums[blockIdx.x] = s[255];
}

__global__ __launch_bounds__(512) void scan2_k(int* __restrict__ bsums) {
    __shared__ int s[512];
    int t = threadIdx.x;
    int v = (t < NPAD / 256) ? bsums[t] : 0;
    s[t] = v;
    __syncthreads();
    #pragma unroll
    for (int d = 1; d < 512; d <<= 1) {
        int a = (t >= d) ? s[t - d] : 0;
        __syncthreads();
        s[t] += a;
        __syncthreads();
    }
    if (t < NPAD / 256) bsums[t] = s[t] - v;
}

__global__ __launch_bounds__(256) void scan3_k(int* __restrict__ offs,
                                               const int* __restrict__ bsums,
                                               int* __restrict__ pos) {
    int i = blockIdx.x * 256 + threadIdx.x;
    int o = offs[i] + bsums[blockIdx.x];
    offs[i] = o;
    pos[i] = o;
}

__global__ __launch_bounds__(256) void fill_k(const int* __restrict__ ei,
                                              int* __restrict__ pos,
                                              int* __restrict__ adj) {
    int e = blockIdx.x * 256 + threadIdx.x;
    if (e >= EE) return;
    int dst = ei[EE + e];
    int p = atomicAdd(&pos[dst], 1);
    adj[p] = ei[e];
}

// ================= gather + GIN combine (bf16) =================
__global__ __launch_bounds__(256) void gather_bf16_k(
    const unsigned short* __restrict__ h, const int* __restrict__ adj,
    const int* __restrict__ offs, const float* __restrict__ epsArr, int l,
    unsigned short* __restrict__ out)
{
    int t = threadIdx.x;
    int c8 = t & 7;
    int n = blockIdx.x * 32 + (t >> 3);
    if (n >= NN) return;
    float epsv = 1.0f + epsArr[l];

    uint4 a = ((const uint4*)(h + (size_t)n * DD))[c8];
    float acc[8], tmp[8];
    unpack8(a, acc);
    #pragma unroll
    for (int j = 0; j < 8; ++j) acc[j] *= epsv;

    int j = offs[n], end = offs[n + 1];
    for (; j + 1 < end; j += 2) {
        int s0 = adj[j], s1 = adj[j + 1];
        uint4 v0 = ((const uint4*)(h + (size_t)s0 * DD))[c8];
        uint4 v1 = ((const uint4*)(h + (size_t)s1 * DD))[c8];
        unpack8(v0, tmp);
        #pragma unroll
        for (int k = 0; k < 8; ++k) acc[k] += tmp[k];
        unpack8(v1, tmp);
        #pragma unroll
        for (int k = 0; k < 8; ++k) acc[k] += tmp[k];
    }
    if (j < end) {
        uint4 v0 = ((const uint4*)(h + (size_t)adj[j] * DD))[c8];
        unpack8(v0, tmp);
        #pragma unroll
        for (int k = 0; k < 8; ++k) acc[k] += tmp[k];
    }
    ((uint4*)(out + (size_t)n * DD))[c8] = pack8(acc);
}

// ================= MFMA GEMM + fused BN-stats =================
template<int MODE>
__global__ __launch_bounds__(256) void gemm_mfma_k(
    const unsigned short* __restrict__ inA,
    const float* __restrict__ ssp,          // scale[64]|shift[64] (MODE 1)
    const unsigned short* __restrict__ wtm, // transposed bf16 W: [c][k]
    const float* __restrict__ bias,
    unsigned short* __restrict__ z,
    float* __restrict__ stats)
{
    const int t = threadIdx.x;
    const int lane = t & 63;
    const int w = t >> 6;
    const int n15 = lane & 15;
    const int quad = lane >> 4;
    const int rowg0 = blockIdx.x * 64 + w * 16;

    U16 bfr[4][2];
    #pragma unroll
    for (int ct = 0; ct < 4; ++ct)
        #pragma unroll
        for (int ks = 0; ks < 2; ++ks)
            bfr[ct][ks].u = *(const uint4*)(wtm + (size_t)(ct * 16 + n15) * 64 + ks * 32 + quad * 8);

    U16 afr[2];
    int arow = rowg0 + n15;
    int arowc = (arow < NN) ? arow : (NN - 1);
    #pragma unroll
    for (int ks = 0; ks < 2; ++ks) {
        uint4 raw = *(const uint4*)(inA + (size_t)arowc * DD + ks * 32 + quad * 8);
        if (MODE == 0) {
            afr[ks].u = raw;
        } else {
            float f[8];
            unpack8(raw, f);
            int k0 = ks * 32 + quad * 8;
            float4 sc0 = *(const float4*)(ssp + k0);
            float4 sc1 = *(const float4*)(ssp + k0 + 4);
            float4 sh0 = *(const float4*)(ssp + 64 + k0);
            float4 sh1 = *(const float4*)(ssp + 64 + k0 + 4);
            f[0] = fmaxf(fmaf(sc0.x, f[0], sh0.x), 0.f);
            f[1] = fmaxf(fmaf(sc0.y, f[1], sh0.y), 0.f);
            f[2] = fmaxf(fmaf(sc0.z, f[2], sh0.z), 0.f);
            f[3] = fmaxf(fmaf(sc0.w, f[3], sh0.w), 0.f);
            f[4] = fmaxf(fmaf(sc1.x, f[4], sh1.x), 0.f);
            f[5] = fmaxf(fmaf(sc1.y, f[5], sh1.y), 0.f);
            f[6] = fmaxf(fmaf(sc1.z, f[6], sh1.z), 0.f);
            f[7] = fmaxf(fmaf(sc1.w, f[7], sh1.w), 0.f);
            afr[ks].u = pack8(f);
        }
    }

    const int copy = blockIdx.x & 31;
    #pragma unroll
    for (int ct = 0; ct < 4; ++ct) {
        f32x4 acc = {0.f, 0.f, 0.f, 0.f};
        acc = __builtin_amdgcn_mfma_f32_16x16x32_bf16(afr[0].h, bfr[ct][0].h, acc, 0, 0, 0);
        acc = __builtin_amdgcn_mfma_f32_16x16x32_bf16(afr[1].h, bfr[ct][1].h, acc, 0, 0, 0);

        int col = ct * 16 + n15;
        float bcol = bias[col];
        float s = 0.f, ss = 0.f;
        #pragma unroll
        for (int r = 0; r < 4; ++r) {
            int rg = rowg0 + quad * 4 + r;
            float v = acc[r] + bcol;
            if (rg < NN) {
                z[(size_t)rg * DD + col] = f2bf_rne(v);
                s += v;
                ss = fmaf(v, v, ss);
            }
        }
        s  += __shfl_xor(s, 16, 64);  s  += __shfl_xor(s, 32, 64);
        ss += __shfl_xor(ss, 16, 64); ss += __shfl_xor(ss, 32, 64);
        if (lane < 16) {
            atomicAdd(&stats[copy * 128 + ct * 16 + lane], s);
            atomicAdd(&stats[copy * 128 + 64 + ct * 16 + lane], ss);
        }
    }
}

// ================= BN finalize (sums 32 shadow copies) =================
__global__ void bn_final_k(const float* __restrict__ sh32,
                           const float* __restrict__ gamma, const float* __restrict__ beta,
                           int off, float* __restrict__ scaleshift)
{
    int f = threadIdx.x;   // 64 threads
    float S = 0.f, SS = 0.f;
    #pragma unroll
    for (int c = 0; c < 32; ++c) {
        S  += sh32[c * 128 + f];
        SS += sh32[c * 128 + 64 + f];
    }
    float inv_n = 1.0f / (float)NN;
    float mean = S * inv_n;
    float var  = SS * inv_n - mean * mean;
    float sc = gamma[off + f] * rsqrtf(var + 1e-5f);
    scaleshift[f] = sc;
    scaleshift[DD + f] = beta[off + f] - sc * mean;
}

// ======== outer BN apply + ReLU + h(bf16) + segmented pooling ========
// lane = feature; quad q owns 64 contiguous nodes; flush on batch-id change.
__global__ __launch_bounds__(256) void apply_bn_pool_k(
    const unsigned short* __restrict__ z2b, const float* __restrict__ ssp,
    const int* __restrict__ batch, unsigned short* __restrict__ hout,
    float* __restrict__ pooled)
{
    int t = threadIdx.x;
    int f = t & 63;
    int q = t >> 6;
    int n0 = blockIdx.x * 256 + q * 64;
    float sc = ssp[f], sh = ssp[DD + f];
    float acc = 0.f;
    int curg = -1;
    for (int i = 0; i < 64; ++i) {
        int n = n0 + i;
        if (n >= NN) break;
        int g = batch[n];                        // wave-uniform load
        if (g != curg) {
            if (curg >= 0) atomicAdd(&pooled[(size_t)curg * DD + f], acc);
            acc = 0.f; curg = g;
        }
        float v = bf2f(z2b[(size_t)n * DD + f]);
        v = fmaxf(fmaf(sc, v, sh), 0.f);
        hout[(size_t)n * DD + f] = f2bf_rne(v);
        acc += v;
    }
    if (curg >= 0) atomicAdd(&pooled[(size_t)curg * DD + f], acc);
}

// ================= jumping-knowledge readout =================
__global__ void readout_k(const float* __restrict__ pooled,
                          const float* __restrict__ Wp, const float* __restrict__ bp,
                          float* __restrict__ out)
{
    int gc = blockIdx.x * blockDim.x + threadIdx.x;
    if (gc >= GG * CC) return;
    int g = gc / CC, c = gc - g * CC;
    float acc = 0.f;
    for (int l = 0; l < LL; ++l) {
        acc += bp[l * CC + c];
        const float* p  = pooled + ((size_t)l * GG + g) * DD;
        const float* wv = Wp + (size_t)l * DD * CC + c;
        #pragma unroll 8
        for (int f = 0; f < DD; ++f) acc = fmaf(p[f], wv[f * CC], acc);
    }
    out[gc] = acc;
}

extern "C" void kernel_launch(void* const* d_in, const int* in_sizes, int n_in,
                              void* d_out, int out_size, void* d_ws, size_t ws_size,
                              hipStream_t stream) {
    const float* x     = (const float*)d_in[0];
    const int*   ei    = (const int*)d_in[1];
    const int*   batch = (const int*)d_in[2];
    const float* eps   = (const float*)d_in[3];
    const float* W1    = (const float*)d_in[4];
    const float* b1    = (const float*)d_in[5];
    const float* g1    = (const float*)d_in[6];
    const float* be1   = (const float*)d_in[7];
    const float* W2    = (const float*)d_in[8];
    const float* b2    = (const float*)d_in[9];
    const float* gout  = (const float*)d_in[10];
    const float* beout = (const float*)d_in[11];
    const float* Wp    = (const float*)d_in[12];
    const float* bp    = (const float*)d_in[13];
    float* out = (float*)d_out;

    float* pooled = (float*)d_ws;                       // LL*GG*DD
    float* stats1 = pooled + (size_t)LL * GG * DD;      // 32*128
    float* stats2 = stats1 + 32 * 128;                  // 32*128
    float* bnp    = stats2 + 32 * 128;                  // 256
    unsigned short* hb    = (unsigned short*)(bnp + 256);
    unsigned short* combA = hb + N64;
    unsigned short* z1b   = combA + N64;
    unsigned short* z2b   = z1b + N64;
    unsigned short* wt    = z2b + N64;                  // 8*4096 bf16
    int* deg   = (int*)(wt + 8 * 4096);
    int* offs  = deg + NPAD + 256;
    int* pos   = offs + NPAD + 256;
    int* bsums = pos + NPAD;
    int* adj   = bsums + 512;

    // ---- prep + layer-0 pooling ----
    hipMemsetAsync(pooled, 0, (size_t)LL * GG * DD * sizeof(float), stream);
    prep_x_pool_k<<<(NN + 255) / 256, 256, 0, stream>>>(x, batch, hb, pooled);
    prep_w_k<<<8, 256, 0, stream>>>(W1, W2, wt);

    // ---- CSR build ----
    hipMemsetAsync(deg, 0, NPAD * sizeof(int), stream);
    hist_k<<<(EE + 255) / 256, 256, 0, stream>>>(ei, deg);
    scan1_k<<<NPAD / 256, 256, 0, stream>>>(deg, offs, bsums);
    scan2_k<<<1, 512, 0, stream>>>(bsums);
    scan3_k<<<NPAD / 256, 256, 0, stream>>>(offs, bsums, pos);
    fill_k<<<(EE + 255) / 256, 256, 0, stream>>>(ei, pos, adj);

    const int gemm_grid = (NN + 63) / 64;
    for (int l = 0; l < LL - 1; ++l) {
        hipMemsetAsync(stats1, 0, 2 * 32 * 128 * sizeof(float), stream);
        gather_bf16_k<<<(NN + 31) / 32, 256, 0, stream>>>(hb, adj, offs, eps, l, combA);
        gemm_mfma_k<0><<<gemm_grid, 256, 0, stream>>>(
            combA, bnp, wt + (size_t)l * 4096, b1 + l * DD, z1b, stats1);
        bn_final_k<<<1, 64, 0, stream>>>(stats1, g1, be1, l * DD, bnp);
        gemm_mfma_k<1><<<gemm_grid, 256, 0, stream>>>(
            z1b, bnp, wt + (size_t)(4 + l) * 4096, b2 + l * DD, z2b, stats2);
        bn_final_k<<<1, 64, 0, stream>>>(stats2, gout, beout, l * DD, bnp + 128);
        apply_bn_pool_k<<<(NN + 255) / 256, 256, 0, stream>>>(
            z2b, bnp + 128, batch, hb, pooled + (size_t)(l + 1) * GG * DD);
    }
    readout_k<<<(GG * CC + 255) / 256, 256, 0, stream>>>(pooled, Wp, bp, out);
}

// Round 5
// 696.471 us; speedup vs baseline: 2.6238x; 1.1848x over previous
//
#include <hip/hip_runtime.h>

#define NN 100000
#define EE 1600000
#define DD 64
#define CC 10
#define GG 512
#define LL 5
#define NPAD 100352            // 392*256
#define N64 (NN * DD)
#define NB 392                 // coarse buckets (256 nodes each)
#define PCH 4096               // edges per partition block
#define BCAP 6144              // per-bucket LDS capacity (mean 4082, >30 sigma)

typedef short bf16x8 __attribute__((ext_vector_type(8)));
typedef float f32x4  __attribute__((ext_vector_type(4)));
union U16 { uint4 u; bf16x8 h; };

__device__ __forceinline__ float bits2f(unsigned int b) { return __uint_as_float(b); }
__device__ __forceinline__ float bf2f(unsigned short s) { return __uint_as_float((unsigned int)s << 16); }
__device__ __forceinline__ unsigned short f2bf_rne(float v) {
    unsigned int b = __float_as_uint(v);
    return (unsigned short)((b + 0x7fffu + ((b >> 16) & 1u)) >> 16);
}
__device__ __forceinline__ void unpack8(uint4 u, float* f) {
    f[0] = bits2f(u.x << 16); f[1] = bits2f(u.x & 0xffff0000u);
    f[2] = bits2f(u.y << 16); f[3] = bits2f(u.y & 0xffff0000u);
    f[4] = bits2f(u.z << 16); f[5] = bits2f(u.z & 0xffff0000u);
    f[6] = bits2f(u.w << 16); f[7] = bits2f(u.w & 0xffff0000u);
}
__device__ __forceinline__ uint4 pack8(const float* f) {
    uint4 u;
    u.x = (unsigned int)f2bf_rne(f[0]) | ((unsigned int)f2bf_rne(f[1]) << 16);
    u.y = (unsigned int)f2bf_rne(f[2]) | ((unsigned int)f2bf_rne(f[3]) << 16);
    u.z = (unsigned int)f2bf_rne(f[4]) | ((unsigned int)f2bf_rne(f[5]) << 16);
    u.w = (unsigned int)f2bf_rne(f[6]) | ((unsigned int)f2bf_rne(f[7]) << 16);
    return u;
}

// ======== prep: x fp32 -> bf16 h, fused layer-0 segmented pooling ========
__global__ __launch_bounds__(256) void prep_x_pool_k(
    const float* __restrict__ x, const int* __restrict__ batch,
    unsigned short* __restrict__ hb, float* __restrict__ pooled)
{
    int t = threadIdx.x;
    int f = t & 63;
    int q = t >> 6;
    int n0 = blockIdx.x * 256 + q * 64;
    float acc = 0.f;
    int curg = -1;
    for (int i = 0; i < 64; ++i) {
        int n = n0 + i;
        if (n >= NN) break;
        int g = batch[n];
        if (g != curg) {
            if (curg >= 0) atomicAdd(&pooled[(size_t)curg * DD + f], acc);
            acc = 0.f; curg = g;
        }
        float v = x[(size_t)n * DD + f];
        hb[(size_t)n * DD + f] = f2bf_rne(v);
        acc += v;
    }
    if (curg >= 0) atomicAdd(&pooled[(size_t)curg * DD + f], acc);
}

// ================= prep: W -> transposed bf16 =================
__global__ __launch_bounds__(256) void prep_w_k(const float* __restrict__ W1,
                                                const float* __restrict__ W2,
                                                unsigned short* __restrict__ wt) {
    int mat = blockIdx.x;
    const float* src = (mat < 4) ? (W1 + (size_t)mat * 4096)
                                 : (W2 + (size_t)(mat - 4) * 4096);
    for (int idx = threadIdx.x; idx < 4096; idx += 256) {
        int c = idx >> 6, k = idx & 63;
        wt[(size_t)mat * 4096 + c * 64 + k] = f2bf_rne(src[k * 64 + c]);
    }
}

// ================= CSR build: coarse hist =================
__global__ __launch_bounds__(256) void bhist_k(const int* __restrict__ ei,
                                               int* __restrict__ bh) {
    __shared__ int cnt[NB];
    for (int i = threadIdx.x; i < NB; i += 256) cnt[i] = 0;
    __syncthreads();
    int stride = gridDim.x * 256;
    for (int e = blockIdx.x * 256 + threadIdx.x; e < EE; e += stride)
        atomicAdd(&cnt[ei[EE + e] >> 8], 1);
    __syncthreads();
    for (int i = threadIdx.x; i < NB; i += 256)
        if (cnt[i]) atomicAdd(&bh[i], cnt[i]);
}

// ================= coarse scan =================
__global__ __launch_bounds__(512) void bscan_k(const int* __restrict__ bh,
                                               int* __restrict__ bo,
                                               int* __restrict__ bcur) {
    __shared__ int s[512];
    int t = threadIdx.x;
    int v = (t < NB) ? bh[t] : 0;
    s[t] = v;
    __syncthreads();
    for (int d = 1; d < 512; d <<= 1) {
        int a = (t >= d) ? s[t - d] : 0;
        __syncthreads();
        s[t] += a;
        __syncthreads();
    }
    int excl = s[t] - v;
    if (t < NB) { bo[t] = excl; bcur[t] = excl; }
    if (t == NB - 1) bo[NB] = excl + v;
}

// ============ partition edges into bucket-contiguous staging ============
__global__ __launch_bounds__(256) void partition_k(const int* __restrict__ ei,
                                                   int* __restrict__ bcur,
                                                   uint2* __restrict__ stage) {
    __shared__ int hist[NB];
    __shared__ int base[NB];
    __shared__ int gbase[NB];
    __shared__ int cnt2[NB];
    __shared__ int scanbuf[512];
    __shared__ uint2 pairs[PCH];
    int t = threadIdx.x;
    int e0 = blockIdx.x * PCH;
    int nE = EE - e0; if (nE > PCH) nE = PCH;

    for (int i = t; i < NB; i += 256) { hist[i] = 0; cnt2[i] = 0; }
    __syncthreads();

    int mys[16], myd[16];
    #pragma unroll
    for (int i = 0; i < 16; ++i) {
        int idx = i * 256 + t;
        if (idx < nE) {
            mys[i] = ei[e0 + idx];
            myd[i] = ei[EE + e0 + idx];
            atomicAdd(&hist[myd[i] >> 8], 1);
        } else myd[i] = -1;
    }
    __syncthreads();

    scanbuf[t]       = (t < NB) ? hist[t] : 0;
    scanbuf[t + 256] = (t + 256 < NB) ? hist[t + 256] : 0;
    __syncthreads();
    for (int d = 1; d < 512; d <<= 1) {
        int a0 = (t >= d) ? scanbuf[t - d] : 0;
        int a1 = ((t + 256) >= d) ? scanbuf[t + 256 - d] : 0;
        __syncthreads();
        scanbuf[t] += a0;
        scanbuf[t + 256] += a1;
        __syncthreads();
    }
    if (t < NB)       base[t]       = scanbuf[t] - hist[t];
    if (t + 256 < NB) base[t + 256] = scanbuf[t + 256] - hist[t + 256];
    __syncthreads();

    #pragma unroll
    for (int i = 0; i < 16; ++i) {
        if (myd[i] >= 0) {
            int b = myd[i] >> 8;
            int p = base[b] + atomicAdd(&cnt2[b], 1);
            pairs[p] = make_uint2((unsigned)mys[i], (unsigned)myd[i]);
        }
    }
    __syncthreads();
    for (int i = t; i < NB; i += 256)
        if (hist[i]) gbase[i] = atomicAdd(&bcur[i], hist[i]);
    __syncthreads();
    for (int p = t; p < nE; p += 256) {
        uint2 pr = pairs[p];
        int b = (int)(pr.y >> 8);
        stage[gbase[b] + (p - base[b])] = pr;
    }
}

// ============ per-bucket CSR: adj + offs, all in LDS ============
__global__ __launch_bounds__(256) void bucket_csr_k(const uint2* __restrict__ stage,
                                                    const int* __restrict__ bo,
                                                    int* __restrict__ adj,
                                                    int* __restrict__ offs) {
    __shared__ int deg[256];
    __shared__ int sb[256];
    __shared__ int nb_[256];
    __shared__ int c2[256];
    __shared__ int loc[BCAP];
    int b = blockIdx.x;
    int s0 = bo[b], s1 = bo[b + 1];
    int cnt = s1 - s0;
    int t = threadIdx.x;

    deg[t] = 0;
    __syncthreads();
    for (int i = t; i < cnt; i += 256) atomicAdd(&deg[stage[s0 + i].y & 255], 1);
    __syncthreads();
    sb[t] = deg[t];
    __syncthreads();
    for (int d = 1; d < 256; d <<= 1) {
        int a = (t >= d) ? sb[t - d] : 0;
        __syncthreads();
        sb[t] += a;
        __syncthreads();
    }
    int nbase = sb[t] - deg[t];
    nb_[t] = nbase;
    c2[t] = 0;
    offs[b * 256 + t] = s0 + nbase;
    __syncthreads();

    if (cnt <= BCAP) {
        for (int i = t; i < cnt; i += 256) {
            uint2 pr = stage[s0 + i];
            int ln = pr.y & 255;
            int p = nb_[ln] + atomicAdd(&c2[ln], 1);
            loc[p] = (int)pr.x;
        }
        __syncthreads();
        for (int i = t; i < cnt; i += 256) adj[s0 + i] = loc[i];
    } else {            // statistically unreachable fallback
        for (int i = t; i < cnt; i += 256) {
            uint2 pr = stage[s0 + i];
            int ln = pr.y & 255;
            int p = nb_[ln] + atomicAdd(&c2[ln], 1);
            adj[s0 + p] = (int)pr.x;
        }
    }
}

// ========== K1: fused gather+combine -> LDS -> MFMA GEMM1 + stats1 ==========
__global__ __launch_bounds__(256) void layer1_k(
    const unsigned short* __restrict__ hb, const int* __restrict__ adj,
    const int* __restrict__ offs, const float* __restrict__ epsArr, int l,
    const unsigned short* __restrict__ wtm, const float* __restrict__ bias,
    unsigned short* __restrict__ z1, float* __restrict__ stats1,
    float* __restrict__ stats2z)
{
    __shared__ unsigned short aLDS[64 * 64];   // 8KB, XOR-swizzled 16B units
    const int t = threadIdx.x;
    const int lane = t & 63;
    const int w = t >> 6;
    const int n15 = lane & 15;
    const int quad = lane >> 4;

    if (blockIdx.x < 32 && t < 128) stats2z[blockIdx.x * 128 + t] = 0.f;

    const float epsv = 1.0f + epsArr[l];
    const int c8 = lane & 7;
    // ---- gather 16 rows per wave (8 lanes/node, 2 iterations) ----
    #pragma unroll
    for (int it = 0; it < 2; ++it) {
        int lr = w * 16 + it * 8 + (lane >> 3);
        int n = blockIdx.x * 64 + lr;
        float acc[8] = {0.f,0.f,0.f,0.f,0.f,0.f,0.f,0.f};
        if (n < NN) {
            float tmp[8];
            uint4 a = *(const uint4*)(hb + (size_t)n * DD + c8 * 8);
            unpack8(a, acc);
            #pragma unroll
            for (int j2 = 0; j2 < 8; ++j2) acc[j2] *= epsv;
            int j = offs[n], end = offs[n + 1];
            for (; j + 1 < end; j += 2) {
                int s0 = adj[j], s1 = adj[j + 1];
                uint4 v0 = *(const uint4*)(hb + (size_t)s0 * DD + c8 * 8);
                uint4 v1 = *(const uint4*)(hb + (size_t)s1 * DD + c8 * 8);
                unpack8(v0, tmp);
                #pragma unroll
                for (int k2 = 0; k2 < 8; ++k2) acc[k2] += tmp[k2];
                unpack8(v1, tmp);
                #pragma unroll
                for (int k2 = 0; k2 < 8; ++k2) acc[k2] += tmp[k2];
            }
            if (j < end) {
                uint4 v0 = *(const uint4*)(hb + (size_t)adj[j] * DD + c8 * 8);
                unpack8(v0, tmp);
                #pragma unroll
                for (int k2 = 0; k2 < 8; ++k2) acc[k2] += tmp[k2];
            }
        }
        int pu = c8 ^ (lr & 7);
        *(uint4*)(aLDS + lr * 64 + pu * 8) = pack8(acc);
    }
    // wave-private rows: in-wave LDS ordering handled by compiler waitcnt

    // ---- A fragments from LDS (swizzled) ----
    U16 afr[2];
    int lr2 = w * 16 + n15;
    #pragma unroll
    for (int ks = 0; ks < 2; ++ks) {
        int pu = (ks * 4 + quad) ^ (lr2 & 7);
        afr[ks].u = *(const uint4*)(aLDS + lr2 * 64 + pu * 8);
    }
    // ---- B fragments from global ----
    U16 bfr[4][2];
    #pragma unroll
    for (int ct = 0; ct < 4; ++ct)
        #pragma unroll
        for (int ks = 0; ks < 2; ++ks)
            bfr[ct][ks].u = *(const uint4*)(wtm + (size_t)(ct * 16 + n15) * 64 + ks * 32 + quad * 8);

    const int rowg0 = blockIdx.x * 64 + w * 16;
    const int copy = blockIdx.x & 31;
    #pragma unroll
    for (int ct = 0; ct < 4; ++ct) {
        f32x4 acc = {0.f, 0.f, 0.f, 0.f};
        acc = __builtin_amdgcn_mfma_f32_16x16x32_bf16(afr[0].h, bfr[ct][0].h, acc, 0, 0, 0);
        acc = __builtin_amdgcn_mfma_f32_16x16x32_bf16(afr[1].h, bfr[ct][1].h, acc, 0, 0, 0);
        int col = ct * 16 + n15;
        float bcol = bias[col];
        float s = 0.f, ss = 0.f;
        #pragma unroll
        for (int r = 0; r < 4; ++r) {
            int rg = rowg0 + quad * 4 + r;
            float v = acc[r] + bcol;
            if (rg < NN) {
                z1[(size_t)rg * DD + col] = f2bf_rne(v);
                s += v;
                ss = fmaf(v, v, ss);
            }
        }
        s  += __shfl_xor(s, 16, 64);  s  += __shfl_xor(s, 32, 64);
        ss += __shfl_xor(ss, 16, 64); ss += __shfl_xor(ss, 32, 64);
        if (lane < 16) {
            atomicAdd(&stats1[copy * 128 + ct * 16 + lane], s);
            atomicAdd(&stats1[copy * 128 + 64 + ct * 16 + lane], ss);
        }
    }
}

// ========== K2: inline BN1 + MFMA GEMM2 + stats2 ==========
__global__ __launch_bounds__(256) void layer2_k(
    const unsigned short* __restrict__ z1, const float* __restrict__ stats1,
    const float* __restrict__ gamma, const float* __restrict__ beta, int off,
    const unsigned short* __restrict__ wtm, const float* __restrict__ bias,
    unsigned short* __restrict__ z2, float* __restrict__ stats2)
{
    __shared__ float ssS[128];
    const int t = threadIdx.x;
    if (t < 64) {
        float S = 0.f, SS = 0.f;
        #pragma unroll
        for (int c = 0; c < 32; ++c) { S += stats1[c * 128 + t]; SS += stats1[c * 128 + 64 + t]; }
        float inv_n = 1.0f / (float)NN;
        float mean = S * inv_n;
        float var  = SS * inv_n - mean * mean;
        float sc = gamma[off + t] * rsqrtf(var + 1e-5f);
        ssS[t] = sc;
        ssS[64 + t] = beta[off + t] - sc * mean;
    }
    __syncthreads();

    const int lane = t & 63;
    const int w = t >> 6;
    const int n15 = lane & 15;
    const int quad = lane >> 4;
    const int rowg0 = blockIdx.x * 64 + w * 16;

    U16 bfr[4][2];
    #pragma unroll
    for (int ct = 0; ct < 4; ++ct)
        #pragma unroll
        for (int ks = 0; ks < 2; ++ks)
            bfr[ct][ks].u = *(const uint4*)(wtm + (size_t)(ct * 16 + n15) * 64 + ks * 32 + quad * 8);

    U16 afr[2];
    int arow = rowg0 + n15;
    int arowc = (arow < NN) ? arow : (NN - 1);
    #pragma unroll
    for (int ks = 0; ks < 2; ++ks) {
        uint4 raw = *(const uint4*)(z1 + (size_t)arowc * DD + ks * 32 + quad * 8);
        float f[8];
        unpack8(raw, f);
        int k0 = ks * 32 + quad * 8;
        #pragma unroll
        for (int j = 0; j < 8; ++j)
            f[j] = fmaxf(fmaf(ssS[k0 + j], f[j], ssS[64 + k0 + j]), 0.f);
        afr[ks].u = pack8(f);
    }

    const int copy = blockIdx.x & 31;
    #pragma unroll
    for (int ct = 0; ct < 4; ++ct) {
        f32x4 acc = {0.f, 0.f, 0.f, 0.f};
        acc = __builtin_amdgcn_mfma_f32_16x16x32_bf16(afr[0].h, bfr[ct][0].h, acc, 0, 0, 0);
        acc = __builtin_amdgcn_mfma_f32_16x16x32_bf16(afr[1].h, bfr[ct][1].h, acc, 0, 0, 0);
        int col = ct * 16 + n15;
        float bcol = bias[col];
        float s = 0.f, ss = 0.f;
        #pragma unroll
        for (int r = 0; r < 4; ++r) {
            int rg = rowg0 + quad * 4 + r;
            float v = acc[r] + bcol;
            if (rg < NN) {
                z2[(size_t)rg * DD + col] = f2bf_rne(v);
                s += v;
                ss = fmaf(v, v, ss);
            }
        }
        s  += __shfl_xor(s, 16, 64);  s  += __shfl_xor(s, 32, 64);
        ss += __shfl_xor(ss, 16, 64); ss += __shfl_xor(ss, 32, 64);
        if (lane < 16) {
            atomicAdd(&stats2[copy * 128 + ct * 16 + lane], s);
            atomicAdd(&stats2[copy * 128 + 64 + ct * 16 + lane], ss);
        }
    }
}

// ========== K3: inline BN2 + ReLU + hb write + segmented pool ==========
__global__ __launch_bounds__(256) void layer3_k(
    const unsigned short* __restrict__ z2, const float* __restrict__ stats2,
    const float* __restrict__ gamma, const float* __restrict__ beta, int off,
    const int* __restrict__ batch, unsigned short* __restrict__ hout,
    float* __restrict__ pooled, float* __restrict__ stats1z)
{
    __shared__ float ssS[128];
    int t = threadIdx.x;
    if (blockIdx.x < 32 && t < 128) stats1z[blockIdx.x * 128 + t] = 0.f;
    if (t < 64) {
        float S = 0.f, SS = 0.f;
        #pragma unroll
        for (int c = 0; c < 32; ++c) { S += stats2[c * 128 + t]; SS += stats2[c * 128 + 64 + t]; }
        float inv_n = 1.0f / (float)NN;
        float mean = S * inv_n;
        float var  = SS * inv_n - mean * mean;
        float sc = gamma[off + t] * rsqrtf(var + 1e-5f);
        ssS[t] = sc;
        ssS[64 + t] = beta[off + t] - sc * mean;
    }
    __syncthreads();

    int f = t & 63;
    int q = t >> 6;
    int n0 = blockIdx.x * 256 + q * 64;
    float sc = ssS[f], sh = ssS[64 + f];
    float acc = 0.f;
    int curg = -1;
    for (int i = 0; i < 64; ++i) {
        int n = n0 + i;
        if (n >= NN) break;
        int g = batch[n];
        if (g != curg) {
            if (curg >= 0) atomicAdd(&pooled[(size_t)curg * DD + f], acc);
            acc = 0.f; curg = g;
        }
        float v = bf2f(z2[(size_t)n * DD + f]);
        v = fmaxf(fmaf(sc, v, sh), 0.f);
        hout[(size_t)n * DD + f] = f2bf_rne(v);
        acc += v;
    }
    if (curg >= 0) atomicAdd(&pooled[(size_t)curg * DD + f], acc);
}

// ================= jumping-knowledge readout =================
__global__ void readout_k(const float* __restrict__ pooled,
                          const float* __restrict__ Wp, const float* __restrict__ bp,
                          float* __restrict__ out)
{
    int gc = blockIdx.x * blockDim.x + threadIdx.x;
    if (gc >= GG * CC) return;
    int g = gc / CC, c = gc - g * CC;
    float acc = 0.f;
    for (int l = 0; l < LL; ++l) {
        acc += bp[l * CC + c];
        const float* p  = pooled + ((size_t)l * GG + g) * DD;
        const float* wv = Wp + (size_t)l * DD * CC + c;
        #pragma unroll 8
        for (int f = 0; f < DD; ++f) acc = fmaf(p[f], wv[f * CC], acc);
    }
    out[gc] = acc;
}

extern "C" void kernel_launch(void* const* d_in, const int* in_sizes, int n_in,
                              void* d_out, int out_size, void* d_ws, size_t ws_size,
                              hipStream_t stream) {
    const float* x     = (const float*)d_in[0];
    const int*   ei    = (const int*)d_in[1];
    const int*   batch = (const int*)d_in[2];
    const float* eps   = (const float*)d_in[3];
    const float* W1    = (const float*)d_in[4];
    const float* b1    = (const float*)d_in[5];
    const float* g1    = (const float*)d_in[6];
    const float* be1   = (const float*)d_in[7];
    const float* W2    = (const float*)d_in[8];
    const float* b2    = (const float*)d_in[9];
    const float* gout  = (const float*)d_in[10];
    const float* beout = (const float*)d_in[11];
    const float* Wp    = (const float*)d_in[12];
    const float* bp    = (const float*)d_in[13];
    float* out = (float*)d_out;

    // ---- workspace layout (16B-aligned sections) ----
    uint2* stage = (uint2*)d_ws;                        // EE*8
    int* adj   = (int*)(stage + EE);                    // EE*4
    int* offs  = adj + EE;                              // (NPAD+256)
    int* bh    = offs + NPAD + 256;                     // 400
    int* bo    = bh + 400;                              // 400
    int* bcur  = bo + 400;                              // 400
    float* pooled = (float*)(bcur + 400);               // LL*GG*DD
    float* stats1 = pooled + (size_t)LL * GG * DD;      // 32*128
    float* stats2 = stats1 + 32 * 128;                  // 32*128
    unsigned short* hb  = (unsigned short*)(stats2 + 32 * 128);
    unsigned short* z1b = hb + N64;
    unsigned short* z2b = z1b + N64;
    unsigned short* wt  = z2b + N64;                    // 8*4096

    // ---- prep + layer-0 pooling ----
    hipMemsetAsync(pooled, 0, ((size_t)LL * GG * DD + 2 * 32 * 128) * sizeof(float), stream);
    prep_x_pool_k<<<(NN + 255) / 256, 256, 0, stream>>>(x, batch, hb, pooled);
    prep_w_k<<<8, 256, 0, stream>>>(W1, W2, wt);

    // ---- CSR build via LDS-staged two-pass partition ----
    hipMemsetAsync(bh, 0, NB * sizeof(int), stream);
    bhist_k<<<512, 256, 0, stream>>>(ei, bh);
    bscan_k<<<1, 512, 0, stream>>>(bh, bo, bcur);
    partition_k<<<(EE + PCH - 1) / PCH, 256, 0, stream>>>(ei, bcur, stage);
    bucket_csr_k<<<NB, 256, 0, stream>>>(stage, bo, adj, offs);

    const int gemm_grid = (NN + 63) / 64;
    const int node_grid = (NN + 255) / 256;
    for (int l = 0; l < LL - 1; ++l) {
        layer1_k<<<gemm_grid, 256, 0, stream>>>(
            hb, adj, offs, eps, l, wt + (size_t)l * 4096, b1 + l * DD, z1b, stats1, stats2);
        layer2_k<<<gemm_grid, 256, 0, stream>>>(
            z1b, stats1, g1, be1, l * DD, wt + (size_t)(4 + l) * 4096, b2 + l * DD, z2b, stats2);
        layer3_k<<<node_grid, 256, 0, stream>>>(
            z2b, stats2, gout, beout, l * DD, batch, hb,
            pooled + (size_t)(l + 1) * GG * DD, stats1);
    }
    readout_k<<<(GG * CC + 255) / 256, 256, 0, stream>>>(pooled, Wp, bp, out);
}

// Round 6
// 653.662 us; speedup vs baseline: 2.7957x; 1.0655x over previous
//
#include <hip/hip_runtime.h>

#define NN 100000
#define EE 1600000
#define DD 64
#define CC 10
#define GG 512
#define LL 5
#define NPAD 100352            // 392*256
#define N64 (NN * DD)
#define NB 392                 // coarse buckets (256 nodes each)
#define PCH 4096               // edges per partition block
#define BCAP 6144              // per-bucket LDS capacity (mean 4082, >30 sigma)
#define SC 8                   // BN stats shadow copies

typedef short bf16x8 __attribute__((ext_vector_type(8)));
typedef float f32x4  __attribute__((ext_vector_type(4)));
union U16 { uint4 u; bf16x8 h; };

__device__ __forceinline__ float bits2f(unsigned int b) { return __uint_as_float(b); }
__device__ __forceinline__ float bf2f(unsigned short s) { return __uint_as_float((unsigned int)s << 16); }
__device__ __forceinline__ unsigned short f2bf_rne(float v) {
    unsigned int b = __float_as_uint(v);
    return (unsigned short)((b + 0x7fffu + ((b >> 16) & 1u)) >> 16);
}
__device__ __forceinline__ void unpack8(uint4 u, float* f) {
    f[0] = bits2f(u.x << 16); f[1] = bits2f(u.x & 0xffff0000u);
    f[2] = bits2f(u.y << 16); f[3] = bits2f(u.y & 0xffff0000u);
    f[4] = bits2f(u.z << 16); f[5] = bits2f(u.z & 0xffff0000u);
    f[6] = bits2f(u.w << 16); f[7] = bits2f(u.w & 0xffff0000u);
}
__device__ __forceinline__ uint4 pack8(const float* f) {
    uint4 u;
    u.x = (unsigned int)f2bf_rne(f[0]) | ((unsigned int)f2bf_rne(f[1]) << 16);
    u.y = (unsigned int)f2bf_rne(f[2]) | ((unsigned int)f2bf_rne(f[3]) << 16);
    u.z = (unsigned int)f2bf_rne(f[4]) | ((unsigned int)f2bf_rne(f[5]) << 16);
    u.w = (unsigned int)f2bf_rne(f[6]) | ((unsigned int)f2bf_rne(f[7]) << 16);
    return u;
}

// ======== prep: x fp32 -> bf16 h, fused layer-0 segmented pooling ========
// wave = one quad segment of 16 contiguous nodes; lane = feature.
__global__ __launch_bounds__(256) void prep_x_pool_k(
    const float* __restrict__ x, const int* __restrict__ batch,
    unsigned short* __restrict__ hb, float* __restrict__ pooled)
{
    int t = threadIdx.x;
    int f = t & 63;
    int q = t >> 6;
    int n0 = blockIdx.x * 64 + q * 16;
    int nmax = NN - n0; if (nmax > 16) nmax = 16;
    float acc = 0.f;
    int curg = -1;
    #pragma unroll 4
    for (int i = 0; i < nmax; ++i) {
        int n = n0 + i;
        int g = batch[n];
        if (g != curg) {
            if (curg >= 0) atomicAdd(&pooled[(size_t)curg * DD + f], acc);
            acc = 0.f; curg = g;
        }
        float v = x[(size_t)n * DD + f];
        hb[(size_t)n * DD + f] = f2bf_rne(v);
        acc += v;
    }
    if (curg >= 0) atomicAdd(&pooled[(size_t)curg * DD + f], acc);
}

// ================= prep: W -> transposed bf16 =================
__global__ __launch_bounds__(256) void prep_w_k(const float* __restrict__ W1,
                                                const float* __restrict__ W2,
                                                unsigned short* __restrict__ wt) {
    int mat = blockIdx.x;
    const float* src = (mat < 4) ? (W1 + (size_t)mat * 4096)
                                 : (W2 + (size_t)(mat - 4) * 4096);
    for (int idx = threadIdx.x; idx < 4096; idx += 256) {
        int c = idx >> 6, k = idx & 63;
        wt[(size_t)mat * 4096 + c * 64 + k] = f2bf_rne(src[k * 64 + c]);
    }
}

// ================= CSR build: coarse hist =================
__global__ __launch_bounds__(256) void bhist_k(const int* __restrict__ ei,
                                               int* __restrict__ bh) {
    __shared__ int cnt[NB];
    for (int i = threadIdx.x; i < NB; i += 256) cnt[i] = 0;
    __syncthreads();
    int stride = gridDim.x * 256;
    for (int e = blockIdx.x * 256 + threadIdx.x; e < EE; e += stride)
        atomicAdd(&cnt[ei[EE + e] >> 8], 1);
    __syncthreads();
    for (int i = threadIdx.x; i < NB; i += 256)
        if (cnt[i]) atomicAdd(&bh[i], cnt[i]);
}

// ================= coarse scan =================
__global__ __launch_bounds__(512) void bscan_k(const int* __restrict__ bh,
                                               int* __restrict__ bo,
                                               int* __restrict__ bcur) {
    __shared__ int s[512];
    int t = threadIdx.x;
    int v = (t < NB) ? bh[t] : 0;
    s[t] = v;
    __syncthreads();
    for (int d = 1; d < 512; d <<= 1) {
        int a = (t >= d) ? s[t - d] : 0;
        __syncthreads();
        s[t] += a;
        __syncthreads();
    }
    int excl = s[t] - v;
    if (t < NB) { bo[t] = excl; bcur[t] = excl; }
    if (t == NB - 1) bo[NB] = excl + v;
}

// ============ partition edges into bucket-contiguous staging ============
__global__ __launch_bounds__(256) void partition_k(const int* __restrict__ ei,
                                                   int* __restrict__ bcur,
                                                   uint2* __restrict__ stage) {
    __shared__ int hist[NB];
    __shared__ int base[NB];
    __shared__ int gbase[NB];
    __shared__ int cnt2[NB];
    __shared__ int scanbuf[512];
    __shared__ uint2 pairs[PCH];
    int t = threadIdx.x;
    int e0 = blockIdx.x * PCH;
    int nE = EE - e0; if (nE > PCH) nE = PCH;

    for (int i = t; i < NB; i += 256) { hist[i] = 0; cnt2[i] = 0; }
    __syncthreads();

    int mys[16], myd[16];
    #pragma unroll
    for (int i = 0; i < 16; ++i) {
        int idx = i * 256 + t;
        if (idx < nE) {
            mys[i] = ei[e0 + idx];
            myd[i] = ei[EE + e0 + idx];
            atomicAdd(&hist[myd[i] >> 8], 1);
        } else myd[i] = -1;
    }
    __syncthreads();

    scanbuf[t]       = (t < NB) ? hist[t] : 0;
    scanbuf[t + 256] = (t + 256 < NB) ? hist[t + 256] : 0;
    __syncthreads();
    for (int d = 1; d < 512; d <<= 1) {
        int a0 = (t >= d) ? scanbuf[t - d] : 0;
        int a1 = ((t + 256) >= d) ? scanbuf[t + 256 - d] : 0;
        __syncthreads();
        scanbuf[t] += a0;
        scanbuf[t + 256] += a1;
        __syncthreads();
    }
    if (t < NB)       base[t]       = scanbuf[t] - hist[t];
    if (t + 256 < NB) base[t + 256] = scanbuf[t + 256] - hist[t + 256];
    __syncthreads();

    #pragma unroll
    for (int i = 0; i < 16; ++i) {
        if (myd[i] >= 0) {
            int b = myd[i] >> 8;
            int p = base[b] + atomicAdd(&cnt2[b], 1);
            pairs[p] = make_uint2((unsigned)mys[i], (unsigned)myd[i]);
        }
    }
    __syncthreads();
    for (int i = t; i < NB; i += 256)
        if (hist[i]) gbase[i] = atomicAdd(&bcur[i], hist[i]);
    __syncthreads();
    for (int p = t; p < nE; p += 256) {
        uint2 pr = pairs[p];
        int b = (int)(pr.y >> 8);
        stage[gbase[b] + (p - base[b])] = pr;
    }
}

// ============ per-bucket CSR: adj + offs, all in LDS ============
__global__ __launch_bounds__(256) void bucket_csr_k(const uint2* __restrict__ stage,
                                                    const int* __restrict__ bo,
                                                    int* __restrict__ adj,
                                                    int* __restrict__ offs) {
    __shared__ int deg[256];
    __shared__ int sb[256];
    __shared__ int nb_[256];
    __shared__ int c2[256];
    __shared__ int loc[BCAP];
    int b = blockIdx.x;
    int s0 = bo[b], s1 = bo[b + 1];
    int cnt = s1 - s0;
    int t = threadIdx.x;

    deg[t] = 0;
    __syncthreads();
    for (int i = t; i < cnt; i += 256) atomicAdd(&deg[stage[s0 + i].y & 255], 1);
    __syncthreads();
    sb[t] = deg[t];
    __syncthreads();
    for (int d = 1; d < 256; d <<= 1) {
        int a = (t >= d) ? sb[t - d] : 0;
        __syncthreads();
        sb[t] += a;
        __syncthreads();
    }
    int nbase = sb[t] - deg[t];
    nb_[t] = nbase;
    c2[t] = 0;
    offs[b * 256 + t] = s0 + nbase;
    __syncthreads();

    if (cnt <= BCAP) {
        for (int i = t; i < cnt; i += 256) {
            uint2 pr = stage[s0 + i];
            int ln = pr.y & 255;
            int p = nb_[ln] + atomicAdd(&c2[ln], 1);
            loc[p] = (int)pr.x;
        }
        __syncthreads();
        for (int i = t; i < cnt; i += 256) adj[s0 + i] = loc[i];
    } else {            // statistically unreachable fallback
        for (int i = t; i < cnt; i += 256) {
            uint2 pr = stage[s0 + i];
            int ln = pr.y & 255;
            int p = nb_[ln] + atomicAdd(&c2[ln], 1);
            adj[s0 + p] = (int)pr.x;
        }
    }
}

// ========== K1: fused gather+combine -> LDS -> MFMA GEMM1 + stats1 ==========
__global__ __launch_bounds__(256) void layer1_k(
    const unsigned short* __restrict__ hb, const int* __restrict__ adj,
    const int* __restrict__ offs, const float* __restrict__ epsArr, int l,
    const unsigned short* __restrict__ wtm, const float* __restrict__ bias,
    unsigned short* __restrict__ z1, float* __restrict__ stats1,
    float* __restrict__ stats2z)
{
    __shared__ unsigned short aLDS[64 * 64];   // 8KB, XOR-swizzled 16B units
    const int t = threadIdx.x;
    const int lane = t & 63;
    const int w = t >> 6;
    const int n15 = lane & 15;
    const int quad = lane >> 4;

    if (blockIdx.x < SC && t < 128) stats2z[blockIdx.x * 128 + t] = 0.f;

    const float epsv = 1.0f + epsArr[l];
    const int c8 = lane & 7;
    // ---- gather 16 rows per wave (8 lanes/node), unroll-4 batched loads ----
    #pragma unroll
    for (int it = 0; it < 2; ++it) {
        int lr = w * 16 + it * 8 + (lane >> 3);
        int n = blockIdx.x * 64 + lr;
        float acc[8] = {0.f,0.f,0.f,0.f,0.f,0.f,0.f,0.f};
        if (n < NN) {
            float tmp[8];
            uint4 a = *(const uint4*)(hb + (size_t)n * DD + c8 * 8);
            unpack8(a, acc);
            #pragma unroll
            for (int j2 = 0; j2 < 8; ++j2) acc[j2] *= epsv;
            int j = offs[n], end = offs[n + 1];
            for (; j + 3 < end; j += 4) {
                int s0 = adj[j], s1 = adj[j + 1], s2 = adj[j + 2], s3 = adj[j + 3];
                uint4 v0 = *(const uint4*)(hb + (size_t)s0 * DD + c8 * 8);
                uint4 v1 = *(const uint4*)(hb + (size_t)s1 * DD + c8 * 8);
                uint4 v2 = *(const uint4*)(hb + (size_t)s2 * DD + c8 * 8);
                uint4 v3 = *(const uint4*)(hb + (size_t)s3 * DD + c8 * 8);
                unpack8(v0, tmp);
                #pragma unroll
                for (int k2 = 0; k2 < 8; ++k2) acc[k2] += tmp[k2];
                unpack8(v1, tmp);
                #pragma unroll
                for (int k2 = 0; k2 < 8; ++k2) acc[k2] += tmp[k2];
                unpack8(v2, tmp);
                #pragma unroll
                for (int k2 = 0; k2 < 8; ++k2) acc[k2] += tmp[k2];
                unpack8(v3, tmp);
                #pragma unroll
                for (int k2 = 0; k2 < 8; ++k2) acc[k2] += tmp[k2];
            }
            for (; j < end; ++j) {
                uint4 v0 = *(const uint4*)(hb + (size_t)adj[j] * DD + c8 * 8);
                unpack8(v0, tmp);
                #pragma unroll
                for (int k2 = 0; k2 < 8; ++k2) acc[k2] += tmp[k2];
            }
        }
        int pu = c8 ^ (lr & 7);
        *(uint4*)(aLDS + lr * 64 + pu * 8) = pack8(acc);
    }

    // ---- A fragments from LDS (swizzled; wave-private rows) ----
    U16 afr[2];
    int lr2 = w * 16 + n15;
    #pragma unroll
    for (int ks = 0; ks < 2; ++ks) {
        int pu = (ks * 4 + quad) ^ (lr2 & 7);
        afr[ks].u = *(const uint4*)(aLDS + lr2 * 64 + pu * 8);
    }
    // ---- B fragments from global ----
    U16 bfr[4][2];
    #pragma unroll
    for (int ct = 0; ct < 4; ++ct)
        #pragma unroll
        for (int ks = 0; ks < 2; ++ks)
            bfr[ct][ks].u = *(const uint4*)(wtm + (size_t)(ct * 16 + n15) * 64 + ks * 32 + quad * 8);

    const int rowg0 = blockIdx.x * 64 + w * 16;
    const int copy = blockIdx.x & (SC - 1);
    #pragma unroll
    for (int ct = 0; ct < 4; ++ct) {
        f32x4 acc = {0.f, 0.f, 0.f, 0.f};
        acc = __builtin_amdgcn_mfma_f32_16x16x32_bf16(afr[0].h, bfr[ct][0].h, acc, 0, 0, 0);
        acc = __builtin_amdgcn_mfma_f32_16x16x32_bf16(afr[1].h, bfr[ct][1].h, acc, 0, 0, 0);
        int col = ct * 16 + n15;
        float bcol = bias[col];
        float s = 0.f, ss = 0.f;
        #pragma unroll
        for (int r = 0; r < 4; ++r) {
            int rg = rowg0 + quad * 4 + r;
            float v = acc[r] + bcol;
            if (rg < NN) {
                z1[(size_t)rg * DD + col] = f2bf_rne(v);
                s += v;
                ss = fmaf(v, v, ss);
            }
        }
        s  += __shfl_xor(s, 16, 64);  s  += __shfl_xor(s, 32, 64);
        ss += __shfl_xor(ss, 16, 64); ss += __shfl_xor(ss, 32, 64);
        if (lane < 16) {
            atomicAdd(&stats1[copy * 128 + ct * 16 + lane], s);
            atomicAdd(&stats1[copy * 128 + 64 + ct * 16 + lane], ss);
        }
    }
}

// ========== K2: inline BN1 + MFMA GEMM2 + stats2 ==========
__global__ __launch_bounds__(256) void layer2_k(
    const unsigned short* __restrict__ z1, const float* __restrict__ stats1,
    const float* __restrict__ gamma, const float* __restrict__ beta, int off,
    const unsigned short* __restrict__ wtm, const float* __restrict__ bias,
    unsigned short* __restrict__ z2, float* __restrict__ stats2)
{
    __shared__ float ssS[128];
    const int t = threadIdx.x;
    if (t < 64) {
        float S = 0.f, SS = 0.f;
        #pragma unroll
        for (int c = 0; c < SC; ++c) { S += stats1[c * 128 + t]; SS += stats1[c * 128 + 64 + t]; }
        float inv_n = 1.0f / (float)NN;
        float mean = S * inv_n;
        float var  = SS * inv_n - mean * mean;
        float sc = gamma[off + t] * rsqrtf(var + 1e-5f);
        ssS[t] = sc;
        ssS[64 + t] = beta[off + t] - sc * mean;
    }
    __syncthreads();

    const int lane = t & 63;
    const int w = t >> 6;
    const int n15 = lane & 15;
    const int quad = lane >> 4;
    const int rowg0 = blockIdx.x * 64 + w * 16;

    U16 bfr[4][2];
    #pragma unroll
    for (int ct = 0; ct < 4; ++ct)
        #pragma unroll
        for (int ks = 0; ks < 2; ++ks)
            bfr[ct][ks].u = *(const uint4*)(wtm + (size_t)(ct * 16 + n15) * 64 + ks * 32 + quad * 8);

    U16 afr[2];
    int arow = rowg0 + n15;
    int arowc = (arow < NN) ? arow : (NN - 1);
    #pragma unroll
    for (int ks = 0; ks < 2; ++ks) {
        uint4 raw = *(const uint4*)(z1 + (size_t)arowc * DD + ks * 32 + quad * 8);
        float f[8];
        unpack8(raw, f);
        int k0 = ks * 32 + quad * 8;
        #pragma unroll
        for (int j = 0; j < 8; ++j)
            f[j] = fmaxf(fmaf(ssS[k0 + j], f[j], ssS[64 + k0 + j]), 0.f);
        afr[ks].u = pack8(f);
    }

    const int copy = blockIdx.x & (SC - 1);
    #pragma unroll
    for (int ct = 0; ct < 4; ++ct) {
        f32x4 acc = {0.f, 0.f, 0.f, 0.f};
        acc = __builtin_amdgcn_mfma_f32_16x16x32_bf16(afr[0].h, bfr[ct][0].h, acc, 0, 0, 0);
        acc = __builtin_amdgcn_mfma_f32_16x16x32_bf16(afr[1].h, bfr[ct][1].h, acc, 0, 0, 0);
        int col = ct * 16 + n15;
        float bcol = bias[col];
        float s = 0.f, ss = 0.f;
        #pragma unroll
        for (int r = 0; r < 4; ++r) {
            int rg = rowg0 + quad * 4 + r;
            float v = acc[r] + bcol;
            if (rg < NN) {
                z2[(size_t)rg * DD + col] = f2bf_rne(v);
                s += v;
                ss = fmaf(v, v, ss);
            }
        }
        s  += __shfl_xor(s, 16, 64);  s  += __shfl_xor(s, 32, 64);
        ss += __shfl_xor(ss, 16, 64); ss += __shfl_xor(ss, 32, 64);
        if (lane < 16) {
            atomicAdd(&stats2[copy * 128 + ct * 16 + lane], s);
            atomicAdd(&stats2[copy * 128 + 64 + ct * 16 + lane], ss);
        }
    }
}

// ========== K3: inline BN2 + ReLU + hb write + segmented pool ==========
// wave = 16 contiguous nodes; lane = feature.
__global__ __launch_bounds__(256) void layer3_k(
    const unsigned short* __restrict__ z2, const float* __restrict__ stats2,
    const float* __restrict__ gamma, const float* __restrict__ beta, int off,
    const int* __restrict__ batch, unsigned short* __restrict__ hout,
    float* __restrict__ pooled, float* __restrict__ stats1z)
{
    __shared__ float ssS[128];
    int t = threadIdx.x;
    if (blockIdx.x < SC && t < 128) stats1z[blockIdx.x * 128 + t] = 0.f;
    if (t < 64) {
        float S = 0.f, SS = 0.f;
        #pragma unroll
        for (int c = 0; c < SC; ++c) { S += stats2[c * 128 + t]; SS += stats2[c * 128 + 64 + t]; }
        float inv_n = 1.0f / (float)NN;
        float mean = S * inv_n;
        float var  = SS * inv_n - mean * mean;
        float sc = gamma[off + t] * rsqrtf(var + 1e-5f);
        ssS[t] = sc;
        ssS[64 + t] = beta[off + t] - sc * mean;
    }
    __syncthreads();

    int f = t & 63;
    int q = t >> 6;
    int n0 = blockIdx.x * 64 + q * 16;
    int nmax = NN - n0; if (nmax > 16) nmax = 16;
    float sc = ssS[f], sh = ssS[64 + f];
    float acc = 0.f;
    int curg = -1;
    #pragma unroll 4
    for (int i = 0; i < nmax; ++i) {
        int n = n0 + i;
        int g = batch[n];
        if (g != curg) {
            if (curg >= 0) atomicAdd(&pooled[(size_t)curg * DD + f], acc);
            acc = 0.f; curg = g;
        }
        float v = bf2f(z2[(size_t)n * DD + f]);
        v = fmaxf(fmaf(sc, v, sh), 0.f);
        hout[(size_t)n * DD + f] = f2bf_rne(v);
        acc += v;
    }
    if (curg >= 0) atomicAdd(&pooled[(size_t)curg * DD + f], acc);
}

// ================= jumping-knowledge readout =================
__global__ void readout_k(const float* __restrict__ pooled,
                          const float* __restrict__ Wp, const float* __restrict__ bp,
                          float* __restrict__ out)
{
    int gc = blockIdx.x * blockDim.x + threadIdx.x;
    if (gc >= GG * CC) return;
    int g = gc / CC, c = gc - g * CC;
    float acc = 0.f;
    for (int l = 0; l < LL; ++l) {
        acc += bp[l * CC + c];
        const float* p  = pooled + ((size_t)l * GG + g) * DD;
        const float* wv = Wp + (size_t)l * DD * CC + c;
        #pragma unroll 8
        for (int f = 0; f < DD; ++f) acc = fmaf(p[f], wv[f * CC], acc);
    }
    out[gc] = acc;
}

extern "C" void kernel_launch(void* const* d_in, const int* in_sizes, int n_in,
                              void* d_out, int out_size, void* d_ws, size_t ws_size,
                              hipStream_t stream) {
    const float* x     = (const float*)d_in[0];
    const int*   ei    = (const int*)d_in[1];
    const int*   batch = (const int*)d_in[2];
    const float* eps   = (const float*)d_in[3];
    const float* W1    = (const float*)d_in[4];
    const float* b1    = (const float*)d_in[5];
    const float* g1    = (const float*)d_in[6];
    const float* be1   = (const float*)d_in[7];
    const float* W2    = (const float*)d_in[8];
    const float* b2    = (const float*)d_in[9];
    const float* gout  = (const float*)d_in[10];
    const float* beout = (const float*)d_in[11];
    const float* Wp    = (const float*)d_in[12];
    const float* bp    = (const float*)d_in[13];
    float* out = (float*)d_out;

    // ---- workspace layout (16B-aligned sections) ----
    uint2* stage = (uint2*)d_ws;                        // EE*8
    int* adj   = (int*)(stage + EE);                    // EE*4
    int* offs  = adj + EE;                              // (NPAD+256)
    int* bh    = offs + NPAD + 256;                     // 400
    int* bo    = bh + 400;                              // 400
    int* bcur  = bo + 400;                              // 400
    float* pooled = (float*)(bcur + 400);               // LL*GG*DD
    float* stats1 = pooled + (size_t)LL * GG * DD;      // SC*128
    float* stats2 = stats1 + SC * 128;                  // SC*128
    unsigned short* hb  = (unsigned short*)(stats2 + SC * 128);
    unsigned short* z1b = hb + N64;
    unsigned short* z2b = z1b + N64;
    unsigned short* wt  = z2b + N64;                    // 8*4096

    // ---- prep + layer-0 pooling ----
    hipMemsetAsync(pooled, 0, ((size_t)LL * GG * DD + 2 * SC * 128) * sizeof(float), stream);
    prep_x_pool_k<<<(NN + 63) / 64, 256, 0, stream>>>(x, batch, hb, pooled);
    prep_w_k<<<8, 256, 0, stream>>>(W1, W2, wt);

    // ---- CSR build via LDS-staged two-pass partition ----
    hipMemsetAsync(bh, 0, NB * sizeof(int), stream);
    bhist_k<<<512, 256, 0, stream>>>(ei, bh);
    bscan_k<<<1, 512, 0, stream>>>(bh, bo, bcur);
    partition_k<<<(EE + PCH - 1) / PCH, 256, 0, stream>>>(ei, bcur, stage);
    bucket_csr_k<<<NB, 256, 0, stream>>>(stage, bo, adj, offs);

    const int gemm_grid = (NN + 63) / 64;
    const int node_grid = (NN + 63) / 64;
    for (int l = 0; l < LL - 1; ++l) {
        layer1_k<<<gemm_grid, 256, 0, stream>>>(
            hb, adj, offs, eps, l, wt + (size_t)l * 4096, b1 + l * DD, z1b, stats1, stats2);
        layer2_k<<<gemm_grid, 256, 0, stream>>>(
            z1b, stats1, g1, be1, l * DD, wt + (size_t)(4 + l) * 4096, b2 + l * DD, z2b, stats2);
        layer3_k<<<node_grid, 256, 0, stream>>>(
            z2b, stats2, gout, beout, l * DD, batch, hb,
            pooled + (size_t)(l + 1) * GG * DD, stats1);
    }
    readout_k<<<(GG * CC + 255) / 256, 256, 0, stream>>>(pooled, Wp, bp, out);
}